// Round 12
// baseline (316.196 us; speedup 1.0000x reference)
//
#include <hip/hip_runtime.h>
#include <hip/hip_fp16.h>
#include <math.h>

#define N_NODES 50000
#define E_EDGES 1600000
#define NE_TOT  (E_EDGES + N_NODES)

// bucketed scatter geometry
#define BSH 7                                   // 128 nodes per bucket
#define NBKT ((N_NODES + 127) >> 7)             // 391 buckets
#define EPW 4096                                // edges per A-pass workgroup
#define NWA ((NE_TOT + EPW - 1) / EPW)          // 403 workgroups

#define CH 128                                  // staged edges per node chunk

// ---------------- fused: per-WG bucket histogram  ||  layer-1 GEMM ----------------

__device__ __forceinline__ void gemm_att_body(
    int bid, int t, float* Wl, float* xs,
    const float* __restrict__ X, const float* __restrict__ W,
    const float* __restrict__ attS, const float* __restrict__ attD,
    __half* __restrict__ H16, float* __restrict__ a_s, float* __restrict__ a_d) {
    int g = t >> 5, cl = t & 31, c4 = cl * 4;
    int rowbase = bid * 32;
    float4 acc[4];
    #pragma unroll
    for (int rr = 0; rr < 4; rr++) acc[rr] = make_float4(0.f, 0.f, 0.f, 0.f);

    for (int kp = 0; kp < 2; kp++) {
        __syncthreads();
        #pragma unroll
        for (int j = 0; j < 8; j++) {
            int f4 = t + 256 * j;
            int kk = f4 >> 5, cg = f4 & 31;
            *(float4*)&Wl[kk * 128 + cg * 4] =
                *(const float4*)&W[(kp * 64 + kk) * 128 + cg * 4];
        }
        #pragma unroll
        for (int j = 0; j < 2; j++) {
            int f4 = t + 256 * j;
            int r = f4 >> 4, k4 = f4 & 15;
            int grow = rowbase + r;
            float4 xv = make_float4(0.f, 0.f, 0.f, 0.f);
            if (grow < N_NODES) xv = *(const float4*)&X[grow * 128 + kp * 64 + k4 * 4];
            *(float4*)&xs[r * 64 + k4 * 4] = xv;
        }
        __syncthreads();
        #pragma unroll
        for (int k4 = 0; k4 < 16; k4++) {
            float4 xv[4];
            #pragma unroll
            for (int rr = 0; rr < 4; rr++)
                xv[rr] = *(float4*)&xs[(g * 4 + rr) * 64 + k4 * 4];
            #pragma unroll
            for (int kk = 0; kk < 4; kk++) {
                float4 wv = *(float4*)&Wl[(k4 * 4 + kk) * 128 + c4];
                #pragma unroll
                for (int rr = 0; rr < 4; rr++) {
                    float xc = (kk == 0) ? xv[rr].x : (kk == 1) ? xv[rr].y
                             : (kk == 2) ? xv[rr].z : xv[rr].w;
                    acc[rr].x += xc * wv.x;
                    acc[rr].y += xc * wv.y;
                    acc[rr].z += xc * wv.z;
                    acc[rr].w += xc * wv.w;
                }
            }
        }
    }

    float4 as4 = *(const float4*)&attS[c4];
    float4 ad4 = *(const float4*)&attD[c4];
    int head = cl >> 3;
    #pragma unroll
    for (int rr = 0; rr < 4; rr++) {
        int grow = rowbase + g * 4 + rr;
        float4 a = acc[rr];
        if (grow < N_NODES) {
            __half2 lo = __floats2half2_rn(a.x, a.y);
            __half2 hi = __floats2half2_rn(a.z, a.w);
            uint2 pk;
            pk.x = *(unsigned int*)&lo;
            pk.y = *(unsigned int*)&hi;
            *(uint2*)&H16[(size_t)grow * 128 + c4] = pk;
        }
        float ps = a.x * as4.x + a.y * as4.y + a.z * as4.z + a.w * as4.w;
        float pd = a.x * ad4.x + a.y * ad4.y + a.z * ad4.z + a.w * ad4.w;
        ps += __shfl_xor(ps, 1); ps += __shfl_xor(ps, 2); ps += __shfl_xor(ps, 4);
        pd += __shfl_xor(pd, 1); pd += __shfl_xor(pd, 2); pd += __shfl_xor(pd, 4);
        if ((cl & 7) == 0 && grow < N_NODES) {
            a_s[grow * 4 + head] = ps;
            a_d[grow * 4 + head] = pd;
        }
    }
}

__global__ __launch_bounds__(256) void k_hist_gemm(
    const int* __restrict__ ei, int* __restrict__ histG,
    const float* __restrict__ X, const float* __restrict__ W,
    const float* __restrict__ attS, const float* __restrict__ attD,
    __half* __restrict__ H16, float* __restrict__ a_s, float* __restrict__ a_d) {
    __shared__ __align__(16) char smem[40960];
    int t = threadIdx.x;
    if (blockIdx.x < NWA) {
        int* h = (int*)smem;
        for (int i = t; i < NBKT; i += 256) h[i] = 0;
        __syncthreads();
        int base = blockIdx.x * EPW;
        #pragma unroll 4
        for (int j = 0; j < EPW / 256; j++) {
            int e = base + t + 256 * j;
            if (e < NE_TOT) {
                int d = (e < E_EDGES) ? ei[E_EDGES + e] : (e - E_EDGES);
                atomicAdd(&h[d >> BSH], 1);
            }
        }
        __syncthreads();
        for (int i = t; i < NBKT; i += 256) histG[blockIdx.x * NBKT + i] = h[i];
    } else {
        float* Wl = (float*)smem;              // 64*128 floats = 32KB
        float* xs = (float*)(smem + 32768);    // 32*64 floats = 8KB
        gemm_att_body(blockIdx.x - NWA, t, Wl, xs, X, W, attS, attD, H16, a_s, a_d);
    }
}

// standalone GEMM (layer 2)
__global__ __launch_bounds__(256) void k_gemm_att(
    const float* __restrict__ X, const float* __restrict__ W,
    const float* __restrict__ attS, const float* __restrict__ attD,
    __half* __restrict__ H16, float* __restrict__ a_s, float* __restrict__ a_d) {
    __shared__ float Wl[64 * 128];
    __shared__ float xs[32 * 64];
    gemm_att_body(blockIdx.x, threadIdx.x, Wl, xs, X, W, attS, attD, H16, a_s, a_d);
}

// ---------------- bucketed CSR build (rest) ----------------

__global__ __launch_bounds__(512) void k_bktscan(int* __restrict__ histG,
                                                 int* __restrict__ bktTotal) {
    __shared__ int sh[512];
    int b = blockIdx.x;            // bucket
    int t = threadIdx.x;           // workgroup index
    int v = (t < NWA) ? histG[t * NBKT + b] : 0;
    sh[t] = v;
    __syncthreads();
    for (int d = 1; d < 512; d <<= 1) {
        int x = (t >= d) ? sh[t - d] : 0;
        __syncthreads();
        sh[t] += x;
        __syncthreads();
    }
    if (t < NWA) histG[t * NBKT + b] = sh[t] - v;   // exclusive
    if (t == 511) bktTotal[b] = sh[511];
}

__global__ __launch_bounds__(512) void k_bktbase(const int* __restrict__ bktTotal,
                                                 int* __restrict__ bktBase,
                                                 int* __restrict__ row_start) {
    __shared__ int sc[512];
    int t = threadIdx.x;
    int v = (t < NBKT) ? bktTotal[t] : 0;
    sc[t] = v;
    __syncthreads();
    for (int d = 1; d < 512; d <<= 1) {
        int x = (t >= d) ? sc[t - d] : 0;
        __syncthreads();
        sc[t] += x;
        __syncthreads();
    }
    if (t < NBKT) bktBase[t] = sc[t] - v;
    if (t == NBKT - 1) { bktBase[NBKT] = sc[t]; row_start[N_NODES] = sc[t]; }
}

// pairs packed as (dst<<16)|src  (both < 65536)
__global__ __launch_bounds__(256) void k_binscatter(const int* __restrict__ ei,
                                                    const int* __restrict__ histG,
                                                    const int* __restrict__ bktBase,
                                                    unsigned int* __restrict__ pairs) {
    __shared__ int lofs[NBKT];
    int t = threadIdx.x;
    for (int i = t; i < NBKT; i += 256)
        lofs[i] = bktBase[i] + histG[blockIdx.x * NBKT + i];
    __syncthreads();
    int base = blockIdx.x * EPW;
    #pragma unroll 4
    for (int j = 0; j < EPW / 256; j++) {
        int e = base + t + 256 * j;
        if (e < NE_TOT) {
            int s, d;
            if (e < E_EDGES) { s = ei[e]; d = ei[E_EDGES + e]; }
            else             { s = d = e - E_EDGES; }
            int pos = atomicAdd(&lofs[d >> BSH], 1);
            pairs[pos] = ((unsigned int)d << 16) | (unsigned int)s;
        }
    }
}

__global__ __launch_bounds__(256) void k_bucketsort(const unsigned int* __restrict__ pairs,
                                                    const int* __restrict__ bktBase,
                                                    int* __restrict__ row_start,
                                                    unsigned short* __restrict__ col) {
    __shared__ int cnt[1 << BSH];
    __shared__ int sc[1 << BSH];
    __shared__ int cur[1 << BSH];
    int b = blockIdx.x, t = threadIdx.x;
    int nbeg = b << BSH;
    int ebeg = bktBase[b], eend = bktBase[b + 1];
    if (t < (1 << BSH)) cnt[t] = 0;
    __syncthreads();
    for (int j = ebeg + t; j < eend; j += 256)
        atomicAdd(&cnt[(int)(pairs[j] >> 16) - nbeg], 1);
    __syncthreads();
    int v = (t < (1 << BSH)) ? cnt[t] : 0;
    if (t < (1 << BSH)) sc[t] = v;
    __syncthreads();
    for (int d = 1; d < (1 << BSH); d <<= 1) {
        int x = 0;
        if (t < (1 << BSH) && t >= d) x = sc[t - d];
        __syncthreads();
        if (t < (1 << BSH)) sc[t] += x;
        __syncthreads();
    }
    if (t < (1 << BSH)) {
        int pos = ebeg + sc[t] - v;      // exclusive
        cur[t] = pos;
        int node = nbeg + t;
        if (node < N_NODES) row_start[node] = pos;
    }
    __syncthreads();
    for (int j = ebeg + t; j < eend; j += 256) {
        unsigned int p = pairs[j];
        int pos = atomicAdd(&cur[(int)(p >> 16) - nbeg], 1);
        col[pos] = (unsigned short)(p & 0xFFFFu);
    }
}

// ---------------- Attention aggregation ----------------

__device__ inline float sel4(float4 v, int i) {
    float r = v.x;
    if (i == 1) r = v.y;
    if (i == 2) r = v.z;
    if (i == 3) r = v.w;
    return r;
}

// p = exp(leaky_relu(a + b)) — no max subtraction (|logits| <~ 2, fp32-safe)
__device__ inline float4 expleaky4(float4 a, float4 b) {
    float4 e, p;
    e.x = a.x + b.x; e.x = e.x > 0.f ? e.x : 0.2f * e.x; p.x = __expf(e.x);
    e.y = a.y + b.y; e.y = e.y > 0.f ? e.y : 0.2f * e.y; p.y = __expf(e.y);
    e.z = a.z + b.z; e.z = e.z > 0.f ? e.z : 0.2f * e.z; p.z = __expf(e.z);
    e.w = a.w + b.w; e.w = e.w > 0.f ? e.w : 0.2f * e.w; p.w = __expf(e.w);
    return p;
}

#define ACC8(q, raw)                                              \
    do {                                                          \
        const __half2* hp_ = (const __half2*)&(raw);              \
        float2 f0_ = __half22float2(hp_[0]);                      \
        float2 f1_ = __half22float2(hp_[1]);                      \
        float2 f2_ = __half22float2(hp_[2]);                      \
        float2 f3_ = __half22float2(hp_[3]);                      \
        acc8[0] = fmaf((q), f0_.x, acc8[0]);                      \
        acc8[1] = fmaf((q), f0_.y, acc8[1]);                      \
        acc8[2] = fmaf((q), f1_.x, acc8[2]);                      \
        acc8[3] = fmaf((q), f1_.y, acc8[3]);                      \
        acc8[4] = fmaf((q), f2_.x, acc8[4]);                      \
        acc8[5] = fmaf((q), f2_.y, acc8[5]);                      \
        acc8[6] = fmaf((q), f3_.x, acc8[6]);                      \
        acc8[7] = fmaf((q), f3_.y, acc8[7]);                      \
    } while (0)

// 256-thread blocks = 4 waves = 2 nodes; TWO waves per node.
// Consume: 8 edge slots (4 per wave) x 16 channel-lanes x 8 ch/lane, 4-deep batch.
template<int MODE>   // 1: layer-1 (ELU -> Hout fp32); 0: layer-2 (fused out-proj)
__global__ __launch_bounds__(256) void k_agg(
    const __half* __restrict__ H16, const float* __restrict__ a_s,
    const float* __restrict__ a_d, const int* __restrict__ row_start,
    const unsigned short* __restrict__ col, const float* __restrict__ bias,
    float* __restrict__ Hout,
    const float* __restrict__ Wout, const float* __restrict__ bout,
    float* __restrict__ out) {
    __shared__ float4 eS[2][CH];      // staged p per node
    __shared__ int    sS[2][CH];      // staged src per node
    __shared__ float  red[2][16][8];  // cross-wave acc combine
    __shared__ float4 sRed[2][2];     // cross-wave denom combine
    __shared__ int    chk[2];         // overflow chunk counts

    int wv = threadIdx.x >> 6;        // 0..3
    int nodeSlot = wv >> 1;           // 0,1
    int wpair = wv & 1;               // wave index within node
    int lane = threadIdx.x & 63;
    int node = blockIdx.x * 2 + nodeSlot;   // N_NODES even: always valid

    int beg = row_start[node], end = row_start[node + 1];
    int deg = end - beg;
    float4 ad4 = *(const float4*)&a_d[node * 4];
    float4* eA = eS[nodeSlot];
    int*    srcA = sS[nodeSlot];

    // co-staging: both waves, stride 128; p = exp(leaky(e)); denom over all edges
    float4 s = make_float4(0.f, 0.f, 0.f, 0.f);
    for (int j = beg + wpair * 64 + lane; j < end; j += 128) {
        int src = (int)col[j];
        float4 av = *(const float4*)&a_s[src * 4];
        float4 p = expleaky4(av, ad4);
        int idx = j - beg;
        if (idx < CH) { srcA[idx] = src; eA[idx] = p; }
        s.x += p.x; s.y += p.y; s.z += p.z; s.w += p.w;
    }
    #pragma unroll
    for (int off = 32; off > 0; off >>= 1) {
        s.x += __shfl_xor(s.x, off);
        s.y += __shfl_xor(s.y, off);
        s.z += __shfl_xor(s.z, off);
        s.w += __shfl_xor(s.w, off);
    }
    int myc = (deg > CH) ? (deg - CH + CH - 1) / CH : 0;
    if (lane == 0) {
        sRed[nodeSlot][wpair] = s;
        if (wpair == 0) chk[nodeSlot] = myc;
    }
    __syncthreads();
    float4 s0 = sRed[nodeSlot][0], s1 = sRed[nodeSlot][1];
    float4 inv;
    inv.x = 1.f / (s0.x + s1.x + 1e-16f);
    inv.y = 1.f / (s0.y + s1.y + 1e-16f);
    inv.z = 1.f / (s0.z + s1.z + 1e-16f);
    inv.w = 1.f / (s0.w + s1.w + 1e-16f);
    int maxc = max(chk[0], chk[1]);

    // consume: slot = wpair*4 + (lane>>4) in [0,8); stride 8; 4-deep batching
    int slot8 = wpair * 4 + (lane >> 4), cl16 = lane & 15, head = cl16 >> 2;
    const __half* hbase = H16 + cl16 * 8;
    const float* pA = (const float*)eA;
    float acc8[8];
    #pragma unroll
    for (int k = 0; k < 8; k++) acc8[k] = 0.f;

    int nst = min(deg, CH);
    int i = slot8;
    for (; i + 24 < nst; i += 32) {
        int t0 = srcA[i];
        int t1 = srcA[i + 8];
        int t2 = srcA[i + 16];
        int t3 = srcA[i + 24];
        float q0 = pA[i * 4 + head];
        float q1 = pA[(i + 8) * 4 + head];
        float q2 = pA[(i + 16) * 4 + head];
        float q3 = pA[(i + 24) * 4 + head];
        float4 r0 = *(const float4*)(hbase + (size_t)t0 * 128);
        float4 r1 = *(const float4*)(hbase + (size_t)t1 * 128);
        float4 r2 = *(const float4*)(hbase + (size_t)t2 * 128);
        float4 r3 = *(const float4*)(hbase + (size_t)t3 * 128);
        ACC8(q0, r0);
        ACC8(q1, r1);
        ACC8(q2, r2);
        ACC8(q3, r3);
    }
    for (; i < nst; i += 8) {
        int src = srcA[i];
        float p = pA[i * 4 + head];
        float4 raw = *(const float4*)(hbase + (size_t)src * 128);
        ACC8(p, raw);
    }
    // overflow chunks (deg > CH, essentially never at Poisson(33); block-uniform loop)
    for (int c = 0; c < maxc; c++) {
        __syncthreads();
        int cb = beg + CH + c * CH;
        if (c < myc) {
            int cnt = min(end - cb, CH);
            for (int idx = wpair * 64 + lane; idx < cnt; idx += 128) {
                int src = (int)col[cb + idx];
                float4 av = *(const float4*)&a_s[src * 4];
                float4 p = expleaky4(av, ad4);
                srcA[idx] = src; eA[idx] = p;
            }
        }
        __syncthreads();
        if (c < myc) {
            int cnt = min(end - cb, CH);
            for (int ii = slot8; ii < cnt; ii += 8) {
                int src = srcA[ii];
                float p = pA[ii * 4 + head];
                float4 raw = *(const float4*)(hbase + (size_t)src * 128);
                ACC8(p, raw);
            }
        }
    }

    // intra-wave slot reduce (lane bits 4,5)
    #pragma unroll
    for (int k = 0; k < 8; k++) {
        acc8[k] += __shfl_xor(acc8[k], 16);
        acc8[k] += __shfl_xor(acc8[k], 32);
    }
    // cross-wave combine
    if (wpair == 1 && lane < 16) {
        #pragma unroll
        for (int k = 0; k < 8; k++) red[nodeSlot][lane][k] = acc8[k];
    }
    __syncthreads();
    if (wpair == 0 && lane < 16) {
        #pragma unroll
        for (int k = 0; k < 8; k++) acc8[k] += red[nodeSlot][lane][k];
        float ih = sel4(inv, head);
        if (MODE == 1) {
            const float* bp = &bias[cl16 * 8];
            float o[8];
            #pragma unroll
            for (int k = 0; k < 8; k++) {
                o[k] = acc8[k] * ih + bp[k];
                o[k] = o[k] > 0.f ? o[k] : expm1f(o[k]);
            }
            float* op = &Hout[(size_t)node * 128 + cl16 * 8];
            *(float4*)&op[0] = make_float4(o[0], o[1], o[2], o[3]);
            *(float4*)&op[4] = make_float4(o[4], o[5], o[6], o[7]);
        } else {
            // fused output projection: 16 lanes hold h2 (8 ch each)
            const float* bp = &bias[cl16 * 8];
            float h2[8];
            #pragma unroll
            for (int k = 0; k < 8; k++) h2[k] = acc8[k] * ih + bp[k];
            float po[8];
            #pragma unroll
            for (int o = 0; o < 8; o++) {
                float t = 0.f;
                #pragma unroll
                for (int k = 0; k < 8; k++)
                    t = fmaf(h2[k], Wout[(cl16 * 8 + k) * 8 + o], t);
                po[o] = t;
            }
            #pragma unroll
            for (int d = 1; d <= 8; d <<= 1) {
                #pragma unroll
                for (int o = 0; o < 8; o++) po[o] += __shfl_xor(po[o], d);
            }
            if (lane == 0) {
                #pragma unroll
                for (int o = 0; o < 8; o++)
                    out[(size_t)node * 8 + o] = po[o] + bout[o];
            }
        }
    }
}

// ---------------- launch ----------------

extern "C" void kernel_launch(void* const* d_in, const int* in_sizes, int n_in,
                              void* d_out, int out_size, void* d_ws, size_t ws_size,
                              hipStream_t stream) {
    const float* x     = (const float*)d_in[0];
    const int*   ei    = (const int*)d_in[1];
    const float* W1    = (const float*)d_in[2];
    const float* attS1 = (const float*)d_in[3];
    const float* attD1 = (const float*)d_in[4];
    const float* b1    = (const float*)d_in[5];
    const float* W2    = (const float*)d_in[6];
    const float* attS2 = (const float*)d_in[7];
    const float* attD2 = (const float*)d_in[8];
    const float* b2    = (const float*)d_in[9];
    const float* Wout  = (const float*)d_in[10];
    const float* bout  = (const float*)d_in[11];
    float* out = (float*)d_out;

    char* ws = (char*)d_ws;
    size_t off = 0;
    auto alloc = [&](size_t bytes) -> void* {
        void* p = ws + off;
        off += (bytes + 255) & ~(size_t)255;
        return p;
    };
    float*          hB        = (float*)alloc((size_t)N_NODES * 128 * 4);
    __half*         h16       = (__half*)alloc((size_t)N_NODES * 128 * 2);
    float*          a_s       = (float*)alloc((size_t)N_NODES * 4 * 4);
    float*          a_d       = (float*)alloc((size_t)N_NODES * 4 * 4);
    int*            row_start = (int*)alloc((size_t)(N_NODES + 1) * 4);
    unsigned short* col       = (unsigned short*)alloc((size_t)NE_TOT * 2);
    int*            histG     = (int*)alloc((size_t)NWA * NBKT * 4);
    int*            bktTotal  = (int*)alloc((size_t)NBKT * 4);
    int*            bktBase   = (int*)alloc((size_t)(NBKT + 1) * 4);
    unsigned int*   pairs     = (unsigned int*)hB;   // alias: hB not live during CSR build

    int nbG = (N_NODES + 31) / 32;
    int nbA = N_NODES / 2;   // 2 nodes per block, N even

    // fused: binhist (blocks 0..NWA) || layer-1 GEMM (blocks NWA..NWA+nbG)
    k_hist_gemm<<<NWA + nbG, 256, 0, stream>>>(ei, histG, x, W1, attS1, attD1,
                                               h16, a_s, a_d);
    k_bktscan<<<NBKT, 512, 0, stream>>>(histG, bktTotal);
    k_bktbase<<<1, 512, 0, stream>>>(bktTotal, bktBase, row_start);
    k_binscatter<<<NWA, 256, 0, stream>>>(ei, histG, bktBase, pairs);
    k_bucketsort<<<NBKT, 256, 0, stream>>>(pairs, bktBase, row_start, col);

    k_agg<1><<<nbA, 256, 0, stream>>>(h16, a_s, a_d, row_start, col, b1, hB,
                                      Wout, bout, out);
    k_gemm_att<<<nbG, 256, 0, stream>>>(hB, W2, attS2, attD2, h16, a_s, a_d);
    k_agg<0><<<nbA, 256, 0, stream>>>(h16, a_s, a_d, row_start, col, b2, hB,
                                      Wout, bout, out);
}

// Round 13
// 254.989 us; speedup vs baseline: 1.2400x; 1.2400x over previous
//
#include <hip/hip_runtime.h>
#include <hip/hip_fp16.h>
#include <math.h>

#define N_NODES 50000
#define E_EDGES 1600000
#define NE_TOT  (E_EDGES + N_NODES)

// bucketed scatter geometry
#define BSH 7                                   // 128 nodes per bucket
#define NBKT ((N_NODES + 127) >> 7)             // 391 buckets
#define EPW 4096                                // edges per A-pass workgroup
#define NWA ((NE_TOT + EPW - 1) / EPW)          // 403 workgroups

#define CH 128                                  // staged edges per node chunk

// ---------------- fused: per-WG bucket histogram  ||  layer-1 GEMM ----------------

__device__ __forceinline__ void gemm_att_body(
    int bid, int t, float* Wl, float* xs,
    const float* __restrict__ X, const float* __restrict__ W,
    const float* __restrict__ attS, const float* __restrict__ attD,
    __half* __restrict__ H16, float* __restrict__ a_s, float* __restrict__ a_d) {
    int g = t >> 5, cl = t & 31, c4 = cl * 4;
    int rowbase = bid * 32;
    float4 acc[4];
    #pragma unroll
    for (int rr = 0; rr < 4; rr++) acc[rr] = make_float4(0.f, 0.f, 0.f, 0.f);

    for (int kp = 0; kp < 2; kp++) {
        __syncthreads();
        #pragma unroll
        for (int j = 0; j < 8; j++) {
            int f4 = t + 256 * j;
            int kk = f4 >> 5, cg = f4 & 31;
            *(float4*)&Wl[kk * 128 + cg * 4] =
                *(const float4*)&W[(kp * 64 + kk) * 128 + cg * 4];
        }
        #pragma unroll
        for (int j = 0; j < 2; j++) {
            int f4 = t + 256 * j;
            int r = f4 >> 4, k4 = f4 & 15;
            int grow = rowbase + r;
            float4 xv = make_float4(0.f, 0.f, 0.f, 0.f);
            if (grow < N_NODES) xv = *(const float4*)&X[grow * 128 + kp * 64 + k4 * 4];
            *(float4*)&xs[r * 64 + k4 * 4] = xv;
        }
        __syncthreads();
        #pragma unroll
        for (int k4 = 0; k4 < 16; k4++) {
            float4 xv[4];
            #pragma unroll
            for (int rr = 0; rr < 4; rr++)
                xv[rr] = *(float4*)&xs[(g * 4 + rr) * 64 + k4 * 4];
            #pragma unroll
            for (int kk = 0; kk < 4; kk++) {
                float4 wv = *(float4*)&Wl[(k4 * 4 + kk) * 128 + c4];
                #pragma unroll
                for (int rr = 0; rr < 4; rr++) {
                    float xc = (kk == 0) ? xv[rr].x : (kk == 1) ? xv[rr].y
                             : (kk == 2) ? xv[rr].z : xv[rr].w;
                    acc[rr].x += xc * wv.x;
                    acc[rr].y += xc * wv.y;
                    acc[rr].z += xc * wv.z;
                    acc[rr].w += xc * wv.w;
                }
            }
        }
    }

    float4 as4 = *(const float4*)&attS[c4];
    float4 ad4 = *(const float4*)&attD[c4];
    int head = cl >> 3;
    #pragma unroll
    for (int rr = 0; rr < 4; rr++) {
        int grow = rowbase + g * 4 + rr;
        float4 a = acc[rr];
        if (grow < N_NODES) {
            __half2 lo = __floats2half2_rn(a.x, a.y);
            __half2 hi = __floats2half2_rn(a.z, a.w);
            uint2 pk;
            pk.x = *(unsigned int*)&lo;
            pk.y = *(unsigned int*)&hi;
            *(uint2*)&H16[(size_t)grow * 128 + c4] = pk;
        }
        float ps = a.x * as4.x + a.y * as4.y + a.z * as4.z + a.w * as4.w;
        float pd = a.x * ad4.x + a.y * ad4.y + a.z * ad4.z + a.w * ad4.w;
        ps += __shfl_xor(ps, 1); ps += __shfl_xor(ps, 2); ps += __shfl_xor(ps, 4);
        pd += __shfl_xor(pd, 1); pd += __shfl_xor(pd, 2); pd += __shfl_xor(pd, 4);
        if ((cl & 7) == 0 && grow < N_NODES) {
            a_s[grow * 4 + head] = ps;
            a_d[grow * 4 + head] = pd;
        }
    }
}

__global__ __launch_bounds__(256) void k_hist_gemm(
    const int* __restrict__ ei, int* __restrict__ histG,
    const float* __restrict__ X, const float* __restrict__ W,
    const float* __restrict__ attS, const float* __restrict__ attD,
    __half* __restrict__ H16, float* __restrict__ a_s, float* __restrict__ a_d) {
    __shared__ __align__(16) char smem[40960];
    int t = threadIdx.x;
    if (blockIdx.x < NWA) {
        int* h = (int*)smem;
        for (int i = t; i < NBKT; i += 256) h[i] = 0;
        __syncthreads();
        int base = blockIdx.x * EPW;
        #pragma unroll 4
        for (int j = 0; j < EPW / 256; j++) {
            int e = base + t + 256 * j;
            if (e < NE_TOT) {
                int d = (e < E_EDGES) ? ei[E_EDGES + e] : (e - E_EDGES);
                atomicAdd(&h[d >> BSH], 1);
            }
        }
        __syncthreads();
        for (int i = t; i < NBKT; i += 256) histG[blockIdx.x * NBKT + i] = h[i];
    } else {
        float* Wl = (float*)smem;              // 64*128 floats = 32KB
        float* xs = (float*)(smem + 32768);    // 32*64 floats = 8KB
        gemm_att_body(blockIdx.x - NWA, t, Wl, xs, X, W, attS, attD, H16, a_s, a_d);
    }
}

// standalone GEMM (layer 2)
__global__ __launch_bounds__(256) void k_gemm_att(
    const float* __restrict__ X, const float* __restrict__ W,
    const float* __restrict__ attS, const float* __restrict__ attD,
    __half* __restrict__ H16, float* __restrict__ a_s, float* __restrict__ a_d) {
    __shared__ float Wl[64 * 128];
    __shared__ float xs[32 * 64];
    gemm_att_body(blockIdx.x, threadIdx.x, Wl, xs, X, W, attS, attD, H16, a_s, a_d);
}

// ---------------- bucketed CSR build (rest) ----------------

__global__ __launch_bounds__(512) void k_bktscan(int* __restrict__ histG,
                                                 int* __restrict__ bktTotal) {
    __shared__ int sh[512];
    int b = blockIdx.x;            // bucket
    int t = threadIdx.x;           // workgroup index
    int v = (t < NWA) ? histG[t * NBKT + b] : 0;
    sh[t] = v;
    __syncthreads();
    for (int d = 1; d < 512; d <<= 1) {
        int x = (t >= d) ? sh[t - d] : 0;
        __syncthreads();
        sh[t] += x;
        __syncthreads();
    }
    if (t < NWA) histG[t * NBKT + b] = sh[t] - v;   // exclusive
    if (t == 511) bktTotal[b] = sh[511];
}

__global__ __launch_bounds__(512) void k_bktbase(const int* __restrict__ bktTotal,
                                                 int* __restrict__ bktBase,
                                                 int* __restrict__ row_start) {
    __shared__ int sc[512];
    int t = threadIdx.x;
    int v = (t < NBKT) ? bktTotal[t] : 0;
    sc[t] = v;
    __syncthreads();
    for (int d = 1; d < 512; d <<= 1) {
        int x = (t >= d) ? sc[t - d] : 0;
        __syncthreads();
        sc[t] += x;
        __syncthreads();
    }
    if (t < NBKT) bktBase[t] = sc[t] - v;
    if (t == NBKT - 1) { bktBase[NBKT] = sc[t]; row_start[N_NODES] = sc[t]; }
}

// pairs packed as (dst<<16)|src  (both < 65536)
__global__ __launch_bounds__(256) void k_binscatter(const int* __restrict__ ei,
                                                    const int* __restrict__ histG,
                                                    const int* __restrict__ bktBase,
                                                    unsigned int* __restrict__ pairs) {
    __shared__ int lofs[NBKT];
    int t = threadIdx.x;
    for (int i = t; i < NBKT; i += 256)
        lofs[i] = bktBase[i] + histG[blockIdx.x * NBKT + i];
    __syncthreads();
    int base = blockIdx.x * EPW;
    #pragma unroll 4
    for (int j = 0; j < EPW / 256; j++) {
        int e = base + t + 256 * j;
        if (e < NE_TOT) {
            int s, d;
            if (e < E_EDGES) { s = ei[e]; d = ei[E_EDGES + e]; }
            else             { s = d = e - E_EDGES; }
            int pos = atomicAdd(&lofs[d >> BSH], 1);
            pairs[pos] = ((unsigned int)d << 16) | (unsigned int)s;
        }
    }
}

__global__ __launch_bounds__(256) void k_bucketsort(const unsigned int* __restrict__ pairs,
                                                    const int* __restrict__ bktBase,
                                                    int* __restrict__ row_start,
                                                    unsigned short* __restrict__ col) {
    __shared__ int cnt[1 << BSH];
    __shared__ int sc[1 << BSH];
    __shared__ int cur[1 << BSH];
    int b = blockIdx.x, t = threadIdx.x;
    int nbeg = b << BSH;
    int ebeg = bktBase[b], eend = bktBase[b + 1];
    if (t < (1 << BSH)) cnt[t] = 0;
    __syncthreads();
    for (int j = ebeg + t; j < eend; j += 256)
        atomicAdd(&cnt[(int)(pairs[j] >> 16) - nbeg], 1);
    __syncthreads();
    int v = (t < (1 << BSH)) ? cnt[t] : 0;
    if (t < (1 << BSH)) sc[t] = v;
    __syncthreads();
    for (int d = 1; d < (1 << BSH); d <<= 1) {
        int x = 0;
        if (t < (1 << BSH) && t >= d) x = sc[t - d];
        __syncthreads();
        if (t < (1 << BSH)) sc[t] += x;
        __syncthreads();
    }
    if (t < (1 << BSH)) {
        int pos = ebeg + sc[t] - v;      // exclusive
        cur[t] = pos;
        int node = nbeg + t;
        if (node < N_NODES) row_start[node] = pos;
    }
    __syncthreads();
    for (int j = ebeg + t; j < eend; j += 256) {
        unsigned int p = pairs[j];
        int pos = atomicAdd(&cur[(int)(p >> 16) - nbeg], 1);
        col[pos] = (unsigned short)(p & 0xFFFFu);
    }
}

// ---------------- Attention aggregation ----------------

__device__ inline float sel4(float4 v, int i) {
    float r = v.x;
    if (i == 1) r = v.y;
    if (i == 2) r = v.z;
    if (i == 3) r = v.w;
    return r;
}

// p = exp(leaky_relu(a + b)) — no max subtraction (|logits| <~ 2, fp32-safe)
__device__ inline float4 expleaky4(float4 a, float4 b) {
    float4 e, p;
    e.x = a.x + b.x; e.x = e.x > 0.f ? e.x : 0.2f * e.x; p.x = __expf(e.x);
    e.y = a.y + b.y; e.y = e.y > 0.f ? e.y : 0.2f * e.y; p.y = __expf(e.y);
    e.z = a.z + b.z; e.z = e.z > 0.f ? e.z : 0.2f * e.z; p.z = __expf(e.z);
    e.w = a.w + b.w; e.w = e.w > 0.f ? e.w : 0.2f * e.w; p.w = __expf(e.w);
    return p;
}

#define ACC8(q, raw)                                              \
    do {                                                          \
        const __half2* hp_ = (const __half2*)&(raw);              \
        float2 f0_ = __half22float2(hp_[0]);                      \
        float2 f1_ = __half22float2(hp_[1]);                      \
        float2 f2_ = __half22float2(hp_[2]);                      \
        float2 f3_ = __half22float2(hp_[3]);                      \
        acc8[0] = fmaf((q), f0_.x, acc8[0]);                      \
        acc8[1] = fmaf((q), f0_.y, acc8[1]);                      \
        acc8[2] = fmaf((q), f1_.x, acc8[2]);                      \
        acc8[3] = fmaf((q), f1_.y, acc8[3]);                      \
        acc8[4] = fmaf((q), f2_.x, acc8[4]);                      \
        acc8[5] = fmaf((q), f2_.y, acc8[5]);                      \
        acc8[6] = fmaf((q), f3_.x, acc8[6]);                      \
        acc8[7] = fmaf((q), f3_.y, acc8[7]);                      \
    } while (0)

// R10-validated geometry: 256-thread blocks = 4 waves = 4 independent nodes;
// consume: 4 edge slots x 16 channel-lanes x 8 ch/lane, 4-deep load batching.
template<int MODE>   // 1: layer-1 (ELU -> Hout fp32); 0: layer-2 (fused out-proj)
__global__ __launch_bounds__(256) void k_agg(
    const __half* __restrict__ H16, const float* __restrict__ a_s,
    const float* __restrict__ a_d, const int* __restrict__ row_start,
    const unsigned short* __restrict__ col, const float* __restrict__ bias,
    float* __restrict__ Hout,
    const float* __restrict__ Wout, const float* __restrict__ bout,
    float* __restrict__ out) {
    __shared__ float4 eS[4][CH];    // staged p per wave
    __shared__ int    sS[4][CH];    // staged src per wave
    __shared__ float  WoT[(MODE == 0) ? 1024 : 1];  // transposed Wout [8][128]
    __shared__ float  boL[(MODE == 0) ? 8 : 1];

    if (MODE == 0) {
        for (int j = threadIdx.x; j < 1024; j += 256) {
            int o = j >> 7, k = j & 127;
            WoT[o * 128 + k] = Wout[k * 8 + o];
        }
        if (threadIdx.x < 8) boL[threadIdx.x] = bout[threadIdx.x];
        __syncthreads();
    }

    int wid = threadIdx.x >> 6;
    int lane = threadIdx.x & 63;
    int node = blockIdx.x * 4 + wid;
    if (node >= N_NODES) return;
    int beg = row_start[node], end = row_start[node + 1];
    int deg = end - beg;
    float4 ad4 = *(const float4*)&a_d[node * 4];
    float4* eA = eS[wid];
    int*    srcA = sS[wid];

    // single pass: p = exp(leaky(e)), stage {src,p} (first CH), accumulate denom
    float4 s = make_float4(0.f, 0.f, 0.f, 0.f);
    for (int j = beg + lane; j < end; j += 64) {
        int src = (int)col[j];
        float4 av = *(const float4*)&a_s[src * 4];
        float4 p = expleaky4(av, ad4);
        int idx = j - beg;
        if (idx < CH) { srcA[idx] = src; eA[idx] = p; }
        s.x += p.x; s.y += p.y; s.z += p.z; s.w += p.w;
    }
    #pragma unroll
    for (int off = 32; off > 0; off >>= 1) {
        s.x += __shfl_xor(s.x, off);
        s.y += __shfl_xor(s.y, off);
        s.z += __shfl_xor(s.z, off);
        s.w += __shfl_xor(s.w, off);
    }
    float4 inv;
    inv.x = 1.f / (s.x + 1e-16f);
    inv.y = 1.f / (s.y + 1e-16f);
    inv.z = 1.f / (s.z + 1e-16f);
    inv.w = 1.f / (s.w + 1e-16f);

    // consume: 4 edge slots x 16 channel-lanes (8 fp16 ch each = 16B load);
    // 4-edge batches per slot for MLP
    int eslot = lane >> 4, cl16 = lane & 15, head = cl16 >> 2;
    const __half* hbase = H16 + cl16 * 8;
    const float* pA = (const float*)eA;
    float acc8[8];
    #pragma unroll
    for (int k = 0; k < 8; k++) acc8[k] = 0.f;

    int nst = min(deg, CH);
    int i = eslot;
    for (; i + 12 < nst; i += 16) {
        int s0 = srcA[i];
        int s1 = srcA[i + 4];
        int s2 = srcA[i + 8];
        int s3 = srcA[i + 12];
        float q0 = pA[i * 4 + head];
        float q1 = pA[(i + 4) * 4 + head];
        float q2 = pA[(i + 8) * 4 + head];
        float q3 = pA[(i + 12) * 4 + head];
        float4 r0 = *(const float4*)(hbase + (size_t)s0 * 128);
        float4 r1 = *(const float4*)(hbase + (size_t)s1 * 128);
        float4 r2 = *(const float4*)(hbase + (size_t)s2 * 128);
        float4 r3 = *(const float4*)(hbase + (size_t)s3 * 128);
        ACC8(q0, r0);
        ACC8(q1, r1);
        ACC8(q2, r2);
        ACC8(q3, r3);
    }
    for (; i < nst; i += 4) {
        int src = srcA[i];
        float p = pA[i * 4 + head];
        float4 raw = *(const float4*)(hbase + (size_t)src * 128);
        ACC8(p, raw);
    }
    // overflow chunks (deg > CH, rare): restage then consume
    for (int cb = beg + CH; cb < end; cb += CH) {
        int cnt = min(end - cb, CH);
        for (int idx = lane; idx < cnt; idx += 64) {
            int src = (int)col[cb + idx];
            float4 av = *(const float4*)&a_s[src * 4];
            float4 p = expleaky4(av, ad4);
            srcA[idx] = src; eA[idx] = p;
        }
        for (int ii = eslot; ii < cnt; ii += 4) {
            int src = srcA[ii];
            float p = pA[ii * 4 + head];
            float4 raw = *(const float4*)(hbase + (size_t)src * 128);
            ACC8(p, raw);
        }
    }

    #pragma unroll
    for (int k = 0; k < 8; k++) {
        acc8[k] += __shfl_xor(acc8[k], 16);
        acc8[k] += __shfl_xor(acc8[k], 32);
    }

    float ih = sel4(inv, head);
    if (MODE == 1) {
        if (eslot == 0) {
            const float* bp = &bias[cl16 * 8];
            float o[8];
            #pragma unroll
            for (int k = 0; k < 8; k++) {
                o[k] = acc8[k] * ih + bp[k];
                o[k] = o[k] > 0.f ? o[k] : expm1f(o[k]);
            }
            float* op = &Hout[(size_t)node * 128 + cl16 * 8];
            *(float4*)&op[0] = make_float4(o[0], o[1], o[2], o[3]);
            *(float4*)&op[4] = make_float4(o[4], o[5], o[6], o[7]);
        }
    } else {
        // fused output projection: h2 = acc*ih + b2 (all lanes hold it),
        // each eslot computes 2 of the 8 outputs
        const float* bp = &bias[cl16 * 8];
        float4 oa, ob;
        oa.x = acc8[0] * ih + bp[0]; oa.y = acc8[1] * ih + bp[1];
        oa.z = acc8[2] * ih + bp[2]; oa.w = acc8[3] * ih + bp[3];
        ob.x = acc8[4] * ih + bp[4]; ob.y = acc8[5] * ih + bp[5];
        ob.z = acc8[6] * ih + bp[6]; ob.w = acc8[7] * ih + bp[7];
        int o0 = eslot * 2;
        float p0 = 0.f, p1 = 0.f;
        {
            float4 wa = *(float4*)&WoT[o0 * 128 + cl16 * 8];
            float4 wb = *(float4*)&WoT[o0 * 128 + cl16 * 8 + 4];
            p0 = oa.x * wa.x + oa.y * wa.y + oa.z * wa.z + oa.w * wa.w
               + ob.x * wb.x + ob.y * wb.y + ob.z * wb.z + ob.w * wb.w;
            float4 wc = *(float4*)&WoT[(o0 + 1) * 128 + cl16 * 8];
            float4 wd = *(float4*)&WoT[(o0 + 1) * 128 + cl16 * 8 + 4];
            p1 = oa.x * wc.x + oa.y * wc.y + oa.z * wc.z + oa.w * wc.w
               + ob.x * wd.x + ob.y * wd.y + ob.z * wd.z + ob.w * wd.w;
        }
        #pragma unroll
        for (int d = 1; d <= 8; d <<= 1) {
            p0 += __shfl_xor(p0, d);
            p1 += __shfl_xor(p1, d);
        }
        if (cl16 == 0) {
            float2 ov = make_float2(p0 + boL[o0], p1 + boL[o0 + 1]);
            *(float2*)&out[(size_t)node * 8 + o0] = ov;
        }
    }
}

// ---------------- launch ----------------

extern "C" void kernel_launch(void* const* d_in, const int* in_sizes, int n_in,
                              void* d_out, int out_size, void* d_ws, size_t ws_size,
                              hipStream_t stream) {
    const float* x     = (const float*)d_in[0];
    const int*   ei    = (const int*)d_in[1];
    const float* W1    = (const float*)d_in[2];
    const float* attS1 = (const float*)d_in[3];
    const float* attD1 = (const float*)d_in[4];
    const float* b1    = (const float*)d_in[5];
    const float* W2    = (const float*)d_in[6];
    const float* attS2 = (const float*)d_in[7];
    const float* attD2 = (const float*)d_in[8];
    const float* b2    = (const float*)d_in[9];
    const float* Wout  = (const float*)d_in[10];
    const float* bout  = (const float*)d_in[11];
    float* out = (float*)d_out;

    char* ws = (char*)d_ws;
    size_t off = 0;
    auto alloc = [&](size_t bytes) -> void* {
        void* p = ws + off;
        off += (bytes + 255) & ~(size_t)255;
        return p;
    };
    float*          hB        = (float*)alloc((size_t)N_NODES * 128 * 4);
    __half*         h16       = (__half*)alloc((size_t)N_NODES * 128 * 2);
    float*          a_s       = (float*)alloc((size_t)N_NODES * 4 * 4);
    float*          a_d       = (float*)alloc((size_t)N_NODES * 4 * 4);
    int*            row_start = (int*)alloc((size_t)(N_NODES + 1) * 4);
    unsigned short* col       = (unsigned short*)alloc((size_t)NE_TOT * 2);
    int*            histG     = (int*)alloc((size_t)NWA * NBKT * 4);
    int*            bktTotal  = (int*)alloc((size_t)NBKT * 4);
    int*            bktBase   = (int*)alloc((size_t)(NBKT + 1) * 4);
    unsigned int*   pairs     = (unsigned int*)hB;   // alias: hB not live during CSR build

    int nbG = (N_NODES + 31) / 32;
    int nbA = (N_NODES + 3) / 4;

    // fused: binhist (blocks 0..NWA) || layer-1 GEMM (blocks NWA..NWA+nbG)
    k_hist_gemm<<<NWA + nbG, 256, 0, stream>>>(ei, histG, x, W1, attS1, attD1,
                                               h16, a_s, a_d);
    k_bktscan<<<NBKT, 512, 0, stream>>>(histG, bktTotal);
    k_bktbase<<<1, 512, 0, stream>>>(bktTotal, bktBase, row_start);
    k_binscatter<<<NWA, 256, 0, stream>>>(ei, histG, bktBase, pairs);
    k_bucketsort<<<NBKT, 256, 0, stream>>>(pairs, bktBase, row_start, col);

    k_agg<1><<<nbA, 256, 0, stream>>>(h16, a_s, a_d, row_start, col, b1, hB,
                                      Wout, bout, out);
    k_gemm_att<<<nbG, 256, 0, stream>>>(hB, W2, attS2, attD2, h16, a_s, a_d);
    k_agg<0><<<nbA, 256, 0, stream>>>(h16, a_s, a_d, row_start, col, b2, hB,
                                      Wout, bout, out);
}